// Round 11
// baseline (349.627 us; speedup 1.0000x reference)
//
#include <hip/hip_runtime.h>
#include <math.h>

// GRUDetector: B=1024, T=512, F=64, H=128, gates (r,z,n), + MLP head (H->32->1).
// R11: R7-R10 all pinned VALU-active at ~60% with VGPR_Count=88: the MFMA
// intrinsic path let the allocator park the 72 weight regs in AGPRs and emit
// accvgpr copies every use (~300+ VALU cyc/step/wave) regardless of +v/+a
// pins. Fix: inline-asm MFMA with ALL operands constrained "v" -> weights,
// u-frags, accumulators FORCED into architectural VGPRs (gfx950 unified file,
// v[] operands legal), zero copies. Demand ~170 < 256 @ 2 waves/SIMD.
// Skeleton = R10: U dbuf, 1 barrier/step, cx-chaining (x-side MFMAs for step
// t+1 issued during step t's gates phase) with ALTERNATING accumulator sets
// (no reg copies). Hazard note: gates read accums 12 movs + 6 MFMAs after the
// last h-MFMA (~70 cyc gap). absmax 9.8e-4 math unchanged.

#define Bsz  1024
#define Tlen 512
#define Fdim 64
#define Hdim 128
#define Gdim 384
#define NB   16
#define NTHR 512
#define NBLK (Bsz / NB)   // 64

typedef __attribute__((ext_vector_type(8))) _Float16 f16x8;
typedef __attribute__((ext_vector_type(4))) _Float16 f16x4;
typedef __attribute__((ext_vector_type(2))) _Float16 f16x2;
typedef __attribute__((ext_vector_type(4))) float    f32x4;

__device__ __forceinline__ float fast_sigmoid(float v) {
    return __builtin_amdgcn_rcpf(1.f + __expf(-v));
}
__device__ __forceinline__ float fast_tanh(float v) {
    return 1.f - 2.f * __builtin_amdgcn_rcpf(__expf(2.f * v) + 1.f);
}

// all-VGPR MFMA: D=C in place; A,B,C forced into arch VGPRs by constraint
#define MFMA_ASM(C, A, B) \
    asm("v_mfma_f32_16x16x32_f16 %0, %1, %2, %0" : "+v"(C) : "v"(A), "v"(B))

__global__ void
__attribute__((amdgpu_flat_work_group_size(NTHR, NTHR), amdgpu_waves_per_eu(2, 2)))
gru_mfma(const float* __restrict__ x,
         const float* __restrict__ W_ih, const float* __restrict__ W_hh,
         const float* __restrict__ b_ih, const float* __restrict__ b_hh,
         const float* __restrict__ W1, const float* __restrict__ b1,
         const float* __restrict__ W2, const float* __restrict__ b2,
         float* __restrict__ out)
{
    __shared__ __align__(16) _Float16 WH[24 * 4 * 4 * 128];  // 98,304 B
    __shared__ __align__(16) _Float16 WI[24 * 2 * 4 * 128];  // 49,152 B
    __shared__ __align__(16) _Float16 U0[6 * 4 * 16 * 8];    //  6,144 B
    __shared__ __align__(16) _Float16 U1[6 * 4 * 16 * 8];    //  6,144 B  (156 KB)

    const int tid  = threadIdx.x;
    const int w    = tid >> 6;        // wave 0..7: gate rows 16w..16w+15
    const int l    = tid & 63;
    const int q    = l >> 4;
    const int bcol = l & 15;
    const int b0   = blockIdx.x * NB;

    // ---- stage W_hh, W_ih into LDS in A-fragment layout (one-time)
    for (int i = tid; i < Gdim * Hdim; i += NTHR) {
        int gr = i >> 7, k = i & 127;
        int idx = (((gr >> 4) * 4 + (k >> 5)) * 4 + ((k & 31) >> 3)) * 128
                + (gr & 15) * 8 + (k & 7);
        WH[idx] = (_Float16)W_hh[i];
    }
    for (int i = tid; i < Gdim * Fdim; i += NTHR) {
        int gr = i >> 6, k = i & 63;
        int idx = (((gr >> 4) * 2 + (k >> 5)) * 4 + ((k & 31) >> 3)) * 128
                + (gr & 15) * 8 + (k & 7);
        WI[idx] = (_Float16)W_ih[i];
    }
    for (int i = tid; i < 2048; i += NTHR) U0[i] = (_Float16)0.f;  // h(0) = 0
    {   // stage x(0) into U0.x
        int e = tid * 2, bx_ = e >> 6, j = e & 63;
        float2 xv = *reinterpret_cast<const float2*>(
            &x[((size_t)(b0 + bx_) * Tlen + 0) * Fdim + j]);
        int kk = 128 + j;
        int idx = (((kk >> 5) * 4 + ((kk & 31) >> 3)) * 16 + bx_) * 8 + (kk & 7);
        U0[idx]     = (_Float16)xv.x;
        U0[idx + 1] = (_Float16)xv.y;
    }

    // ---- per-lane biases (gate rows 16w + q*4 + j)
    float br[4], bz[4], bnh[4], bnx[4];
    #pragma unroll
    for (int j = 0; j < 4; ++j) {
        int gr = 16 * w + q * 4 + j;
        br[j]  = b_ih[gr] + b_hh[gr];
        bz[j]  = b_ih[Hdim + gr] + b_hh[Hdim + gr];
        bnh[j] = b_hh[2 * Hdim + gr];
        bnx[j] = b_ih[2 * Hdim + gr];
    }

    float hp0 = 0.f, hp1 = 0.f, hp2 = 0.f, hp3 = 0.f;

    const int kb    = 16 * w + 4 * q;
    const int hbase = (((kb >> 5) * 4 + ((kb & 31) >> 3)) * 16 + bcol) * 8 + (kb & 7);

    const int e_x = tid * 2, bx = e_x >> 6, jx = e_x & 63;
    const int kx  = 128 + jx;
    const int xidx = (((kx >> 5) * 4 + ((kx & 31) >> 3)) * 16 + bx) * 8 + (kx & 7);
    const float* xsrc = &x[(size_t)(b0 + bx) * Tlen * Fdim + jx];

    __syncthreads();

#define WHF(gt, kt) (*reinterpret_cast<const f16x8*>(&WH[((((gt)*4+(kt))*4+q)*128) + (l&15)*8]))
#define WIF(gt, kt) (*reinterpret_cast<const f16x8*>(&WI[((((gt)*2+(kt))*4+q)*128) + (l&15)*8]))

    // ---- load 18 weight fragments once (asm "v" constraints force VGPRs)
    f16x8 whr0 = WHF(w, 0),      whr1 = WHF(w, 1),      whr2 = WHF(w, 2),      whr3 = WHF(w, 3);
    f16x8 whz0 = WHF(8 + w, 0),  whz1 = WHF(8 + w, 1),  whz2 = WHF(8 + w, 2),  whz3 = WHF(8 + w, 3);
    f16x8 whn0 = WHF(16 + w, 0), whn1 = WHF(16 + w, 1), whn2 = WHF(16 + w, 2), whn3 = WHF(16 + w, 3);
    f16x8 wir0 = WIF(w, 0),      wir1 = WIF(w, 1);
    f16x8 wiz0 = WIF(8 + w, 0),  wiz1 = WIF(8 + w, 1);
    f16x8 win0 = WIF(16 + w, 0), win1 = WIF(16 + w, 1);

    // ---- pre-loop: x-contribution accumulators (set A) for t=0 from x(0)
    f32x4 cxrA = {br[0], br[1], br[2], br[3]};
    f32x4 cxzA = {bz[0], bz[1], bz[2], bz[3]};
    f32x4 cxnA = {bnx[0], bnx[1], bnx[2], bnx[3]};
    {
        f16x8 ub4 = *reinterpret_cast<const f16x8*>(&U0[((4*4+q)*16 + bcol)*8]);
        f16x8 ub5 = *reinterpret_cast<const f16x8*>(&U0[((5*4+q)*16 + bcol)*8]);
        MFMA_ASM(cxrA, wir0, ub4); MFMA_ASM(cxrA, wir1, ub5);
        MFMA_ASM(cxzA, wiz0, ub4); MFMA_ASM(cxzA, wiz1, ub5);
        MFMA_ASM(cxnA, win0, ub4); MFMA_ASM(cxnA, win1, ub5);
    }
    f32x4 cxrB = {0.f,0.f,0.f,0.f}, cxzB = {0.f,0.f,0.f,0.f}, cxnB = {0.f,0.f,0.f,0.f};
    __syncthreads();               // x(0) frag reads done before overwrite

    {   // restage U0.x with x(1)
        float2 x1 = *reinterpret_cast<const float2*>(xsrc + (size_t)1 * Fdim);
        f16x2 xq = {(_Float16)x1.x, (_Float16)x1.y};
        *reinterpret_cast<f16x2*>(&U0[xidx]) = xq;
    }
    // xp holds x(t+2) entering step t
    float2 xp = *reinterpret_cast<const float2*>(xsrc + (size_t)2 * Fdim);
    __syncthreads();

    // one GRU step: cx* = this step's (bias + x-contrib); dx* = next step's,
    // accumulated during the gates phase from Ur's x-region (= x(t+1)).
    auto step = [&](const _Float16* __restrict__ Ur, _Float16* __restrict__ Uw, int t,
                    f32x4& cxr, f32x4& cxz, f32x4& cxn,
                    f32x4& dxr, f32x4& dxz, f32x4& dxn) {
        // in-loop pins: loop-carried opaque values -> no remat
        asm volatile("" : "+v"(whr0), "+v"(whr1), "+v"(whr2), "+v"(whr3),
                          "+v"(whz0), "+v"(whz1));
        asm volatile("" : "+v"(whz2), "+v"(whz3), "+v"(whn0), "+v"(whn1),
                          "+v"(whn2), "+v"(whn3));
        asm volatile("" : "+v"(wir0), "+v"(wir1), "+v"(wiz0), "+v"(wiz1),
                          "+v"(win0), "+v"(win1));

        // u fragments: h first (critical path), then x(t+1)
        f16x8 ub0 = *reinterpret_cast<const f16x8*>(&Ur[((0*4+q)*16 + bcol)*8]);
        f16x8 ub1 = *reinterpret_cast<const f16x8*>(&Ur[((1*4+q)*16 + bcol)*8]);
        f16x8 ub2 = *reinterpret_cast<const f16x8*>(&Ur[((2*4+q)*16 + bcol)*8]);
        f16x8 ub3 = *reinterpret_cast<const f16x8*>(&Ur[((3*4+q)*16 + bcol)*8]);
        f16x8 ub4 = *reinterpret_cast<const f16x8*>(&Ur[((4*4+q)*16 + bcol)*8]);
        f16x8 ub5 = *reinterpret_cast<const f16x8*>(&Ur[((5*4+q)*16 + bcol)*8]);

        float2 xw = xp;                                   // x(t+2)
        if (t + 3 < Tlen)
            xp = *reinterpret_cast<const float2*>(xsrc + (size_t)(t + 3) * Fdim);

        f32x4 cnh = {bnh[0], bnh[1], bnh[2], bnh[3]};

        // 12 h-MFMAs chained on ready cx accumulators (r,z,n round-robin)
        MFMA_ASM(cxr, whr0, ub0); MFMA_ASM(cxz, whz0, ub0); MFMA_ASM(cnh, whn0, ub0);
        MFMA_ASM(cxr, whr1, ub1); MFMA_ASM(cxz, whz1, ub1); MFMA_ASM(cnh, whn1, ub1);
        MFMA_ASM(cxr, whr2, ub2); MFMA_ASM(cxz, whz2, ub2); MFMA_ASM(cnh, whn2, ub2);
        MFMA_ASM(cxr, whr3, ub3); MFMA_ASM(cxz, whz3, ub3); MFMA_ASM(cnh, whn3, ub3);

        // next-step x contributions (fills MFMA pipe + hazard gap before reads)
        dxr = f32x4{br[0], br[1], br[2], br[3]};
        dxz = f32x4{bz[0], bz[1], bz[2], bz[3]};
        dxn = f32x4{bnx[0], bnx[1], bnx[2], bnx[3]};
        MFMA_ASM(dxr, wir0, ub4); MFMA_ASM(dxz, wiz0, ub4); MFMA_ASM(dxn, win0, ub4);
        MFMA_ASM(dxr, wir1, ub5); MFMA_ASM(dxz, wiz1, ub5); MFMA_ASM(dxn, win1, ub5);

        // gates (accumulators are plain VGPRs: direct reads, no copies)
        float r0 = fast_sigmoid(cxr[0]), z0 = fast_sigmoid(cxz[0]);
        float r1 = fast_sigmoid(cxr[1]), z1 = fast_sigmoid(cxz[1]);
        float r2 = fast_sigmoid(cxr[2]), z2 = fast_sigmoid(cxz[2]);
        float r3 = fast_sigmoid(cxr[3]), z3 = fast_sigmoid(cxz[3]);
        float n0 = fast_tanh(cxn[0] + r0 * cnh[0]);
        float n1 = fast_tanh(cxn[1] + r1 * cnh[1]);
        float n2 = fast_tanh(cxn[2] + r2 * cnh[2]);
        float n3 = fast_tanh(cxn[3] + r3 * cnh[3]);
        hp0 = n0 + z0 * (hp0 - n0);
        hp1 = n1 + z1 * (hp1 - n1);
        hp2 = n2 + z2 * (hp2 - n2);
        hp3 = n3 + z3 * (hp3 - n3);

        f16x4 hq = {(_Float16)hp0, (_Float16)hp1, (_Float16)hp2, (_Float16)hp3};
        *reinterpret_cast<f16x4*>(&Uw[hbase]) = hq;

        if (t + 2 < Tlen) {                               // stage x(t+2)
            f16x2 xq = {(_Float16)xw.x, (_Float16)xw.y};
            *reinterpret_cast<f16x2*>(&Uw[xidx]) = xq;
        }
        __syncthreads();   // single barrier: Uw complete, Ur reads done
    };

    #pragma unroll 1
    for (int t = 0; t < Tlen; t += 2) {
        step(U0, U1, t,     cxrA, cxzA, cxnA, cxrB, cxzB, cxnB);
        step(U1, U0, t + 1, cxrB, cxzB, cxnB, cxrA, cxzA, cxnA);
    }
    // final h(T) in U0

    // ---- epilogue MLP: hidden = relu(hT @ W1.T + b1); out = hidden @ W2.T + b2
    {
        int m = tid & 31, b = tid >> 5;
        float acc = b1[m];
        #pragma unroll 8
        for (int k = 0; k < Hdim; ++k) {
            int ui = (((k >> 5) * 4 + ((k & 31) >> 3)) * 16 + b) * 8 + (k & 7);
            acc += W1[m * Hdim + k] * (float)U0[ui];
        }
        float v = W2[m] * fmaxf(acc, 0.f);
        v += __shfl_xor(v, 1,  32);
        v += __shfl_xor(v, 2,  32);
        v += __shfl_xor(v, 4,  32);
        v += __shfl_xor(v, 8,  32);
        v += __shfl_xor(v, 16, 32);
        if (m == 0) out[b0 + b] = v + b2[0];
    }
}

extern "C" void kernel_launch(void* const* d_in, const int* in_sizes, int n_in,
                              void* d_out, int out_size, void* d_ws, size_t ws_size,
                              hipStream_t stream)
{
    const float* x    = (const float*)d_in[0];
    const float* W_ih = (const float*)d_in[1];
    const float* W_hh = (const float*)d_in[2];
    const float* b_ih = (const float*)d_in[3];
    const float* b_hh = (const float*)d_in[4];
    const float* W1   = (const float*)d_in[5];
    const float* b1   = (const float*)d_in[6];
    const float* W2   = (const float*)d_in[7];
    const float* b2   = (const float*)d_in[8];
    float* out = (float*)d_out;

    dim3 grid(NBLK), block(NTHR);
    hipLaunchKernelGGL(gru_mfma, grid, block, 0, stream,
                       x, W_ih, W_hh, b_ih, b_hh, W1, b1, W2, b2, out);
}

// Round 12
// 349.184 us; speedup vs baseline: 1.0013x; 1.0013x over previous
//
#include <hip/hip_runtime.h>
#include <math.h>

// GRUDetector: B=1024, T=512, F=64, H=128, gates (r,z,n), + MLP head (H->32->1).
// R12: R7-R11 all ~1550 cyc/step. Model fitting all rounds: the 2 waves/SIMD
// are PHASE-ALIGNED (lockstep barrier + round-robin issue): MFMA phases
// interleave and finish together (~700 cyc), then both waves' gates serialize
// on VALU (~560). Fix: anti-phase the waves with s_setprio (T5's mechanism,
// role diversity created explicitly): "leader" waves (one per SIMD under
// either w%4 or w/2 pairing: (w^(w>>2))&1) run at prio 1 -> finish MFMAs
// ~350 early, run gates while laggard MFMAs fill the pipe. MFMA asm volatile
// so nothing reorders across setprio. Base = R11 (asm MFMA, dbuf U, 1 barrier,
// cx-chaining, lookahead x prefetch). absmax 9.8e-4 math unchanged.

#define Bsz  1024
#define Tlen 512
#define Fdim 64
#define Hdim 128
#define Gdim 384
#define NB   16
#define NTHR 512
#define NBLK (Bsz / NB)   // 64

typedef __attribute__((ext_vector_type(8))) _Float16 f16x8;
typedef __attribute__((ext_vector_type(4))) _Float16 f16x4;
typedef __attribute__((ext_vector_type(2))) _Float16 f16x2;
typedef __attribute__((ext_vector_type(4))) float    f32x4;

__device__ __forceinline__ float fast_sigmoid(float v) {
    return __builtin_amdgcn_rcpf(1.f + __expf(-v));
}
__device__ __forceinline__ float fast_tanh(float v) {
    return 1.f - 2.f * __builtin_amdgcn_rcpf(__expf(2.f * v) + 1.f);
}

// all-VGPR MFMA, volatile: fixed order relative to setprio + each other
#define MFMA_ASM(C, A, B) \
    asm volatile("v_mfma_f32_16x16x32_f16 %0, %1, %2, %0" : "+v"(C) : "v"(A), "v"(B))

__global__ void
__attribute__((amdgpu_flat_work_group_size(NTHR, NTHR), amdgpu_waves_per_eu(2, 2)))
gru_mfma(const float* __restrict__ x,
         const float* __restrict__ W_ih, const float* __restrict__ W_hh,
         const float* __restrict__ b_ih, const float* __restrict__ b_hh,
         const float* __restrict__ W1, const float* __restrict__ b1,
         const float* __restrict__ W2, const float* __restrict__ b2,
         float* __restrict__ out)
{
    __shared__ __align__(16) _Float16 WH[24 * 4 * 4 * 128];  // 98,304 B
    __shared__ __align__(16) _Float16 WI[24 * 2 * 4 * 128];  // 49,152 B
    __shared__ __align__(16) _Float16 U0[6 * 4 * 16 * 8];    //  6,144 B
    __shared__ __align__(16) _Float16 U1[6 * 4 * 16 * 8];    //  6,144 B  (156 KB)

    const int tid  = threadIdx.x;
    const int w    = tid >> 6;        // wave 0..7: gate rows 16w..16w+15
    const int l    = tid & 63;
    const int q    = l >> 4;
    const int bcol = l & 15;
    const int b0   = blockIdx.x * NB;
    const bool lead = ((w ^ (w >> 2)) & 1) == 0;   // one leader per SIMD pair

    // ---- stage W_hh, W_ih into LDS in A-fragment layout (one-time)
    for (int i = tid; i < Gdim * Hdim; i += NTHR) {
        int gr = i >> 7, k = i & 127;
        int idx = (((gr >> 4) * 4 + (k >> 5)) * 4 + ((k & 31) >> 3)) * 128
                + (gr & 15) * 8 + (k & 7);
        WH[idx] = (_Float16)W_hh[i];
    }
    for (int i = tid; i < Gdim * Fdim; i += NTHR) {
        int gr = i >> 6, k = i & 63;
        int idx = (((gr >> 4) * 2 + (k >> 5)) * 4 + ((k & 31) >> 3)) * 128
                + (gr & 15) * 8 + (k & 7);
        WI[idx] = (_Float16)W_ih[i];
    }
    for (int i = tid; i < 2048; i += NTHR) U0[i] = (_Float16)0.f;  // h(0) = 0
    {   // stage x(0) into U0.x
        int e = tid * 2, bx_ = e >> 6, j = e & 63;
        float2 xv = *reinterpret_cast<const float2*>(
            &x[((size_t)(b0 + bx_) * Tlen + 0) * Fdim + j]);
        int kk = 128 + j;
        int idx = (((kk >> 5) * 4 + ((kk & 31) >> 3)) * 16 + bx_) * 8 + (kk & 7);
        U0[idx]     = (_Float16)xv.x;
        U0[idx + 1] = (_Float16)xv.y;
    }

    // ---- per-lane biases (gate rows 16w + q*4 + j)
    float br[4], bz[4], bnh[4], bnx[4];
    #pragma unroll
    for (int j = 0; j < 4; ++j) {
        int gr = 16 * w + q * 4 + j;
        br[j]  = b_ih[gr] + b_hh[gr];
        bz[j]  = b_ih[Hdim + gr] + b_hh[Hdim + gr];
        bnh[j] = b_hh[2 * Hdim + gr];
        bnx[j] = b_ih[2 * Hdim + gr];
    }

    float hp0 = 0.f, hp1 = 0.f, hp2 = 0.f, hp3 = 0.f;

    const int kb    = 16 * w + 4 * q;
    const int hbase = (((kb >> 5) * 4 + ((kb & 31) >> 3)) * 16 + bcol) * 8 + (kb & 7);

    const int e_x = tid * 2, bx = e_x >> 6, jx = e_x & 63;
    const int kx  = 128 + jx;
    const int xidx = (((kx >> 5) * 4 + ((kx & 31) >> 3)) * 16 + bx) * 8 + (kx & 7);
    const float* xsrc = &x[(size_t)(b0 + bx) * Tlen * Fdim + jx];

    __syncthreads();

#define WHF(gt, kt) (*reinterpret_cast<const f16x8*>(&WH[((((gt)*4+(kt))*4+q)*128) + (l&15)*8]))
#define WIF(gt, kt) (*reinterpret_cast<const f16x8*>(&WI[((((gt)*2+(kt))*4+q)*128) + (l&15)*8]))

    // ---- load 18 weight fragments once
    f16x8 whr0 = WHF(w, 0),      whr1 = WHF(w, 1),      whr2 = WHF(w, 2),      whr3 = WHF(w, 3);
    f16x8 whz0 = WHF(8 + w, 0),  whz1 = WHF(8 + w, 1),  whz2 = WHF(8 + w, 2),  whz3 = WHF(8 + w, 3);
    f16x8 whn0 = WHF(16 + w, 0), whn1 = WHF(16 + w, 1), whn2 = WHF(16 + w, 2), whn3 = WHF(16 + w, 3);
    f16x8 wir0 = WIF(w, 0),      wir1 = WIF(w, 1);
    f16x8 wiz0 = WIF(8 + w, 0),  wiz1 = WIF(8 + w, 1);
    f16x8 win0 = WIF(16 + w, 0), win1 = WIF(16 + w, 1);

    // ---- pre-loop: x-contribution accumulators (set A) for t=0 from x(0)
    f32x4 cxrA = {br[0], br[1], br[2], br[3]};
    f32x4 cxzA = {bz[0], bz[1], bz[2], bz[3]};
    f32x4 cxnA = {bnx[0], bnx[1], bnx[2], bnx[3]};
    {
        f16x8 ub4 = *reinterpret_cast<const f16x8*>(&U0[((4*4+q)*16 + bcol)*8]);
        f16x8 ub5 = *reinterpret_cast<const f16x8*>(&U0[((5*4+q)*16 + bcol)*8]);
        MFMA_ASM(cxrA, wir0, ub4); MFMA_ASM(cxrA, wir1, ub5);
        MFMA_ASM(cxzA, wiz0, ub4); MFMA_ASM(cxzA, wiz1, ub5);
        MFMA_ASM(cxnA, win0, ub4); MFMA_ASM(cxnA, win1, ub5);
    }
    f32x4 cxrB = {0.f,0.f,0.f,0.f}, cxzB = {0.f,0.f,0.f,0.f}, cxnB = {0.f,0.f,0.f,0.f};
    __syncthreads();               // x(0) frag reads done before overwrite

    {   // restage U0.x with x(1)
        float2 x1 = *reinterpret_cast<const float2*>(xsrc + (size_t)1 * Fdim);
        f16x2 xq = {(_Float16)x1.x, (_Float16)x1.y};
        *reinterpret_cast<f16x2*>(&U0[xidx]) = xq;
    }
    // xp holds x(t+2) entering step t
    float2 xp = *reinterpret_cast<const float2*>(xsrc + (size_t)2 * Fdim);
    __syncthreads();

    auto step = [&](const _Float16* __restrict__ Ur, _Float16* __restrict__ Uw, int t,
                    f32x4& cxr, f32x4& cxz, f32x4& cxn,
                    f32x4& dxr, f32x4& dxz, f32x4& dxn) {
        if (lead) __builtin_amdgcn_s_setprio(1);   // leaders run the step first

        // in-loop pins: loop-carried opaque values -> no remat
        asm volatile("" : "+v"(whr0), "+v"(whr1), "+v"(whr2), "+v"(whr3),
                          "+v"(whz0), "+v"(whz1));
        asm volatile("" : "+v"(whz2), "+v"(whz3), "+v"(whn0), "+v"(whn1),
                          "+v"(whn2), "+v"(whn3));
        asm volatile("" : "+v"(wir0), "+v"(wir1), "+v"(wiz0), "+v"(wiz1),
                          "+v"(win0), "+v"(win1));

        // u fragments: h first (critical path), then x(t+1)
        f16x8 ub0 = *reinterpret_cast<const f16x8*>(&Ur[((0*4+q)*16 + bcol)*8]);
        f16x8 ub1 = *reinterpret_cast<const f16x8*>(&Ur[((1*4+q)*16 + bcol)*8]);
        f16x8 ub2 = *reinterpret_cast<const f16x8*>(&Ur[((2*4+q)*16 + bcol)*8]);
        f16x8 ub3 = *reinterpret_cast<const f16x8*>(&Ur[((3*4+q)*16 + bcol)*8]);
        f16x8 ub4 = *reinterpret_cast<const f16x8*>(&Ur[((4*4+q)*16 + bcol)*8]);
        f16x8 ub5 = *reinterpret_cast<const f16x8*>(&Ur[((5*4+q)*16 + bcol)*8]);

        float2 xw = xp;                                   // x(t+2)
        if (t + 3 < Tlen)
            xp = *reinterpret_cast<const float2*>(xsrc + (size_t)(t + 3) * Fdim);

        f32x4 cnh = {bnh[0], bnh[1], bnh[2], bnh[3]};

        // 12 h-MFMAs chained on ready cx accumulators
        MFMA_ASM(cxr, whr0, ub0); MFMA_ASM(cxz, whz0, ub0); MFMA_ASM(cnh, whn0, ub0);
        MFMA_ASM(cxr, whr1, ub1); MFMA_ASM(cxz, whz1, ub1); MFMA_ASM(cnh, whn1, ub1);
        MFMA_ASM(cxr, whr2, ub2); MFMA_ASM(cxz, whz2, ub2); MFMA_ASM(cnh, whn2, ub2);
        MFMA_ASM(cxr, whr3, ub3); MFMA_ASM(cxz, whz3, ub3); MFMA_ASM(cnh, whn3, ub3);

        // next-step x contributions (fill pipe + hazard gap before accum reads)
        dxr = f32x4{br[0], br[1], br[2], br[3]};
        dxz = f32x4{bz[0], bz[1], bz[2], bz[3]};
        dxn = f32x4{bnx[0], bnx[1], bnx[2], bnx[3]};
        MFMA_ASM(dxr, wir0, ub4); MFMA_ASM(dxz, wiz0, ub4); MFMA_ASM(dxn, win0, ub4);
        MFMA_ASM(dxr, wir1, ub5); MFMA_ASM(dxz, wiz1, ub5); MFMA_ASM(dxn, win1, ub5);

        // gates
        float r0 = fast_sigmoid(cxr[0]), z0 = fast_sigmoid(cxz[0]);
        float r1 = fast_sigmoid(cxr[1]), z1 = fast_sigmoid(cxz[1]);
        float r2 = fast_sigmoid(cxr[2]), z2 = fast_sigmoid(cxz[2]);
        float r3 = fast_sigmoid(cxr[3]), z3 = fast_sigmoid(cxz[3]);
        float n0 = fast_tanh(cxn[0] + r0 * cnh[0]);
        float n1 = fast_tanh(cxn[1] + r1 * cnh[1]);
        float n2 = fast_tanh(cxn[2] + r2 * cnh[2]);
        float n3 = fast_tanh(cxn[3] + r3 * cnh[3]);
        hp0 = n0 + z0 * (hp0 - n0);
        hp1 = n1 + z1 * (hp1 - n1);
        hp2 = n2 + z2 * (hp2 - n2);
        hp3 = n3 + z3 * (hp3 - n3);

        f16x4 hq = {(_Float16)hp0, (_Float16)hp1, (_Float16)hp2, (_Float16)hp3};
        *reinterpret_cast<f16x4*>(&Uw[hbase]) = hq;

        if (t + 2 < Tlen) {                               // stage x(t+2)
            f16x2 xq = {(_Float16)xw.x, (_Float16)xw.y};
            *reinterpret_cast<f16x2*>(&Uw[xidx]) = xq;
        }
        if (lead) __builtin_amdgcn_s_setprio(0);   // equal priority at barrier
        __syncthreads();   // single barrier: Uw complete, Ur reads done
    };

    #pragma unroll 1
    for (int t = 0; t < Tlen; t += 2) {
        step(U0, U1, t,     cxrA, cxzA, cxnA, cxrB, cxzB, cxnB);
        step(U1, U0, t + 1, cxrB, cxzB, cxnB, cxrA, cxzA, cxnA);
    }
    // final h(T) in U0

    // ---- epilogue MLP: hidden = relu(hT @ W1.T + b1); out = hidden @ W2.T + b2
    {
        int m = tid & 31, b = tid >> 5;
        float acc = b1[m];
        #pragma unroll 8
        for (int k = 0; k < Hdim; ++k) {
            int ui = (((k >> 5) * 4 + ((k & 31) >> 3)) * 16 + b) * 8 + (k & 7);
            acc += W1[m * Hdim + k] * (float)U0[ui];
        }
        float v = W2[m] * fmaxf(acc, 0.f);
        v += __shfl_xor(v, 1,  32);
        v += __shfl_xor(v, 2,  32);
        v += __shfl_xor(v, 4,  32);
        v += __shfl_xor(v, 8,  32);
        v += __shfl_xor(v, 16, 32);
        if (m == 0) out[b0 + b] = v + b2[0];
    }
}

extern "C" void kernel_launch(void* const* d_in, const int* in_sizes, int n_in,
                              void* d_out, int out_size, void* d_ws, size_t ws_size,
                              hipStream_t stream)
{
    const float* x    = (const float*)d_in[0];
    const float* W_ih = (const float*)d_in[1];
    const float* W_hh = (const float*)d_in[2];
    const float* b_ih = (const float*)d_in[3];
    const float* b_hh = (const float*)d_in[4];
    const float* W1   = (const float*)d_in[5];
    const float* b1   = (const float*)d_in[6];
    const float* W2   = (const float*)d_in[7];
    const float* b2   = (const float*)d_in[8];
    float* out = (float*)d_out;

    dim3 grid(NBLK), block(NTHR);
    hipLaunchKernelGGL(gru_mfma, grid, block, 0, stream,
                       x, W_ih, W_hh, b_ih, b_hh, W1, b1, W2, b2, out);
}

// Round 13
// 329.963 us; speedup vs baseline: 1.0596x; 1.0583x over previous
//
#include <hip/hip_runtime.h>
#include <math.h>

// GRUDetector: B=1024, T=512, F=64, H=128, gates (r,z,n), + MLP head (H->32->1).
// R13: R10/R11/R12 nulls falsified copy-tax/reg-class/priority theories. The
// invariant: every step's x-prefetch global load is in flight at the step's
// __syncthreads(), which emits s_waitcnt vmcnt(0) lgkmcnt(0) before s_barrier
// (m97 lesson) -> every step eats an exposed HBM round trip. Fix: raw barrier
// "s_waitcnt lgkmcnt(0); s_barrier" (LDS ordering only; global loads stay in
// flight, per-use vmcnt covers them). Also: weights gathered ONE-TIME from
// GLOBAL into per-lane registers (no LDS weight arrays, no remat source, no
// pins; LDS 156KB -> 12KB). Base = R7 skeleton: dbuf U, 1 barrier/step,
// lookahead-2 x prefetch, intrinsic MFMA, f32 gates (absmax 9.8e-4).

#define Bsz  1024
#define Tlen 512
#define Fdim 64
#define Hdim 128
#define Gdim 384
#define NB   16
#define NTHR 512
#define NBLK (Bsz / NB)   // 64

typedef __attribute__((ext_vector_type(8))) _Float16 f16x8;
typedef __attribute__((ext_vector_type(4))) _Float16 f16x4;
typedef __attribute__((ext_vector_type(2))) _Float16 f16x2;
typedef __attribute__((ext_vector_type(4))) float    f32x4;

__device__ __forceinline__ float fast_sigmoid(float v) {
    return __builtin_amdgcn_rcpf(1.f + __expf(-v));
}
__device__ __forceinline__ float fast_tanh(float v) {
    return 1.f - 2.f * __builtin_amdgcn_rcpf(__expf(2.f * v) + 1.f);
}

// barrier that orders LDS only: NO vmcnt drain (global prefetch stays in flight)
#define BAR_LDS() do {                                                   \
    __builtin_amdgcn_sched_barrier(0);                                   \
    asm volatile("s_waitcnt lgkmcnt(0)\n\ts_barrier" ::: "memory");      \
    __builtin_amdgcn_sched_barrier(0);                                   \
} while (0)

__global__ void
__attribute__((amdgpu_flat_work_group_size(NTHR, NTHR), amdgpu_waves_per_eu(2, 2)))
gru_mfma(const float* __restrict__ x,
         const float* __restrict__ W_ih, const float* __restrict__ W_hh,
         const float* __restrict__ b_ih, const float* __restrict__ b_hh,
         const float* __restrict__ W1, const float* __restrict__ b1,
         const float* __restrict__ W2, const float* __restrict__ b2,
         float* __restrict__ out)
{
    __shared__ __align__(16) _Float16 U0[6 * 4 * 16 * 8];    // 6,144 B
    __shared__ __align__(16) _Float16 U1[6 * 4 * 16 * 8];    // 6,144 B (12.3 KB total)

    const int tid  = threadIdx.x;
    const int w    = tid >> 6;        // wave 0..7: gate rows 16w..16w+15
    const int l    = tid & 63;
    const int q    = l >> 4;
    const int bcol = l & 15;
    const int b0   = blockIdx.x * NB;

    // ---- init h(0)=0 and stage x(0) into U0
    for (int i = tid; i < 2048; i += NTHR) U0[i] = (_Float16)0.f;
    {
        int e = tid * 2, bx_ = e >> 6, j = e & 63;
        float2 xv = *reinterpret_cast<const float2*>(
            &x[((size_t)(b0 + bx_) * Tlen + 0) * Fdim + j]);
        int kk = 128 + j;
        int idx = (((kk >> 5) * 4 + ((kk & 31) >> 3)) * 16 + bx_) * 8 + (kk & 7);
        U0[idx]     = (_Float16)xv.x;
        U0[idx + 1] = (_Float16)xv.y;
    }

    // ---- per-lane biases (gate rows 16w + q*4 + j)
    float br[4], bz[4], bnh[4], bnx[4];
    #pragma unroll
    for (int j = 0; j < 4; ++j) {
        int gr = 16 * w + q * 4 + j;
        br[j]  = b_ih[gr] + b_hh[gr];
        bz[j]  = b_ih[Hdim + gr] + b_hh[Hdim + gr];
        bnh[j] = b_hh[2 * Hdim + gr];
        bnx[j] = b_ih[2 * Hdim + gr];
    }

    float hp0 = 0.f, hp1 = 0.f, hp2 = 0.f, hp3 = 0.f;

    const int kb    = 16 * w + 4 * q;
    const int hbase = (((kb >> 5) * 4 + ((kb & 31) >> 3)) * 16 + bcol) * 8 + (kb & 7);

    const int e_x = tid * 2, bx = e_x >> 6, jx = e_x & 63;
    const int kx  = 128 + jx;
    const int xidx = (((kx >> 5) * 4 + ((kx & 31) >> 3)) * 16 + bx) * 8 + (kx & 7);
    const float* xsrc = &x[(size_t)(b0 + bx) * Tlen * Fdim + jx];

    // ---- one-time: gather 18 weight fragments from GLOBAL into registers.
    // A-frag (gt,kt): lane supplies row 16*gt+(l&15), k = kt*32 + q*8 + 0..7.
    const int rr = l & 15;
    auto LDWH = [&](int gt, int kt) -> f16x8 {
        const float* p = W_hh + (size_t)(16 * gt + rr) * Hdim + kt * 32 + q * 8;
        float4 a = *reinterpret_cast<const float4*>(p);
        float4 b = *reinterpret_cast<const float4*>(p + 4);
        f16x8 r = {(_Float16)a.x, (_Float16)a.y, (_Float16)a.z, (_Float16)a.w,
                   (_Float16)b.x, (_Float16)b.y, (_Float16)b.z, (_Float16)b.w};
        return r;
    };
    auto LDWI = [&](int gt, int kt) -> f16x8 {
        const float* p = W_ih + (size_t)(16 * gt + rr) * Fdim + kt * 32 + q * 8;
        float4 a = *reinterpret_cast<const float4*>(p);
        float4 b = *reinterpret_cast<const float4*>(p + 4);
        f16x8 r = {(_Float16)a.x, (_Float16)a.y, (_Float16)a.z, (_Float16)a.w,
                   (_Float16)b.x, (_Float16)b.y, (_Float16)b.z, (_Float16)b.w};
        return r;
    };
    f16x8 whr0 = LDWH(w, 0),      whr1 = LDWH(w, 1),      whr2 = LDWH(w, 2),      whr3 = LDWH(w, 3);
    f16x8 whz0 = LDWH(8 + w, 0),  whz1 = LDWH(8 + w, 1),  whz2 = LDWH(8 + w, 2),  whz3 = LDWH(8 + w, 3);
    f16x8 whn0 = LDWH(16 + w, 0), whn1 = LDWH(16 + w, 1), whn2 = LDWH(16 + w, 2), whn3 = LDWH(16 + w, 3);
    f16x8 wir0 = LDWI(w, 0),      wir1 = LDWI(w, 1);
    f16x8 wiz0 = LDWI(8 + w, 0),  wiz1 = LDWI(8 + w, 1);
    f16x8 win0 = LDWI(16 + w, 0), win1 = LDWI(16 + w, 1);

    __syncthreads();   // one-time full barrier (U0 staged; drains gathers too)

#define MFMA(a, b, c) __builtin_amdgcn_mfma_f32_16x16x32_f16((a), (b), (c), 0, 0, 0)

    // x prefetch: xp holds x(t+1) entering step t
    float2 xp = *reinterpret_cast<const float2*>(xsrc + (size_t)1 * Fdim);

    auto step = [&](const _Float16* __restrict__ Ur, _Float16* __restrict__ Uw, int t) {
        // u fragments (h: 4 tiles, x: 2 tiles)
        f16x8 ub0 = *reinterpret_cast<const f16x8*>(&Ur[((0*4+q)*16 + bcol)*8]);
        f16x8 ub1 = *reinterpret_cast<const f16x8*>(&Ur[((1*4+q)*16 + bcol)*8]);
        f16x8 ub2 = *reinterpret_cast<const f16x8*>(&Ur[((2*4+q)*16 + bcol)*8]);
        f16x8 ub3 = *reinterpret_cast<const f16x8*>(&Ur[((3*4+q)*16 + bcol)*8]);
        f16x8 ub4 = *reinterpret_cast<const f16x8*>(&Ur[((4*4+q)*16 + bcol)*8]);
        f16x8 ub5 = *reinterpret_cast<const f16x8*>(&Ur[((5*4+q)*16 + bcol)*8]);

        float2 xw = xp;                                   // x(t+1), loaded a step ago
        if (t + 2 < Tlen)                                 // issue x(t+2); in flight
            xp = *reinterpret_cast<const float2*>(xsrc + (size_t)(t + 2) * Fdim);

        f32x4 cr  = {br[0],  br[1],  br[2],  br[3]};
        f32x4 cz  = {bz[0],  bz[1],  bz[2],  bz[3]};
        f32x4 cnh = {bnh[0], bnh[1], bnh[2], bnh[3]};
        f32x4 cnx = {bnx[0], bnx[1], bnx[2], bnx[3]};

        cr  = MFMA(whr0, ub0, cr);
        cz  = MFMA(whz0, ub0, cz);
        cnh = MFMA(whn0, ub0, cnh);
        cr  = MFMA(whr1, ub1, cr);
        cz  = MFMA(whz1, ub1, cz);
        cnh = MFMA(whn1, ub1, cnh);
        cr  = MFMA(whr2, ub2, cr);
        cz  = MFMA(whz2, ub2, cz);
        cnh = MFMA(whn2, ub2, cnh);
        cr  = MFMA(whr3, ub3, cr);
        cz  = MFMA(whz3, ub3, cz);
        cnh = MFMA(whn3, ub3, cnh);
        cr  = MFMA(wir0, ub4, cr);
        cz  = MFMA(wiz0, ub4, cz);
        cnx = MFMA(win0, ub4, cnx);
        cr  = MFMA(wir1, ub5, cr);
        cz  = MFMA(wiz1, ub5, cz);
        cnx = MFMA(win1, ub5, cnx);

        float r0 = fast_sigmoid(cr[0]), z0 = fast_sigmoid(cz[0]);
        float r1 = fast_sigmoid(cr[1]), z1 = fast_sigmoid(cz[1]);
        float r2 = fast_sigmoid(cr[2]), z2 = fast_sigmoid(cz[2]);
        float r3 = fast_sigmoid(cr[3]), z3 = fast_sigmoid(cz[3]);
        float n0 = fast_tanh(cnx[0] + r0 * cnh[0]);
        float n1 = fast_tanh(cnx[1] + r1 * cnh[1]);
        float n2 = fast_tanh(cnx[2] + r2 * cnh[2]);
        float n3 = fast_tanh(cnx[3] + r3 * cnh[3]);
        hp0 = n0 + z0 * (hp0 - n0);
        hp1 = n1 + z1 * (hp1 - n1);
        hp2 = n2 + z2 * (hp2 - n2);
        hp3 = n3 + z3 * (hp3 - n3);

        f16x4 hq = {(_Float16)hp0, (_Float16)hp1, (_Float16)hp2, (_Float16)hp3};
        *reinterpret_cast<f16x4*>(&Uw[hbase]) = hq;

        if (t + 1 < Tlen) {
            f16x2 xq = {(_Float16)xw.x, (_Float16)xw.y};
            *reinterpret_cast<f16x2*>(&Uw[xidx]) = xq;
        }
        BAR_LDS();   // LDS-only barrier: global prefetch NOT drained
    };

    #pragma unroll 1
    for (int t = 0; t < Tlen; t += 2) {
        step(U0, U1, t);
        step(U1, U0, t + 1);
    }
    // final h(T) in U0

    // ---- epilogue MLP: hidden = relu(hT @ W1.T + b1); out = hidden @ W2.T + b2
    {
        int m = tid & 31, b = tid >> 5;
        float acc = b1[m];
        #pragma unroll 8
        for (int k = 0; k < Hdim; ++k) {
            int ui = (((k >> 5) * 4 + ((k & 31) >> 3)) * 16 + b) * 8 + (k & 7);
            acc += W1[m * Hdim + k] * (float)U0[ui];
        }
        float v = W2[m] * fmaxf(acc, 0.f);
        v += __shfl_xor(v, 1,  32);
        v += __shfl_xor(v, 2,  32);
        v += __shfl_xor(v, 4,  32);
        v += __shfl_xor(v, 8,  32);
        v += __shfl_xor(v, 16, 32);
        if (m == 0) out[b0 + b] = v + b2[0];
    }
}

extern "C" void kernel_launch(void* const* d_in, const int* in_sizes, int n_in,
                              void* d_out, int out_size, void* d_ws, size_t ws_size,
                              hipStream_t stream)
{
    const float* x    = (const float*)d_in[0];
    const float* W_ih = (const float*)d_in[1];
    const float* W_hh = (const float*)d_in[2];
    const float* b_ih = (const float*)d_in[3];
    const float* b_hh = (const float*)d_in[4];
    const float* W1   = (const float*)d_in[5];
    const float* b1   = (const float*)d_in[6];
    const float* W2   = (const float*)d_in[7];
    const float* b2   = (const float*)d_in[8];
    float* out = (float*)d_out;

    dim3 grid(NBLK), block(NTHR);
    hipLaunchKernelGGL(gru_mfma, grid, block, 0, stream,
                       x, W_ih, W_hh, b_ih, b_hh, W1, b1, W2, b2, out);
}